// Round 1
// 514.468 us; speedup vs baseline: 1.1340x; 1.1340x over previous
//
#include <hip/hip_runtime.h>

// Combi layer: diff-stencil 1x1 conv + truncated spectral conv.
// B=16, C=32 (in=out), H=W=256, modes M1=M2=32.
// Spectral path via partial DFTs (only 64 kx x 32 ky modes needed).
// R1: k_dftw rewritten as bf16 MFMA GEMM with hi/lo split-precision
//     (error-compensated: x_hi*e_hi + x_hi*e_lo + x_lo*e_hi, fp32 accum).

#define PI2_256 0.02454369260617026f   // 2*pi/256

__device__ __forceinline__ unsigned short bf16r(float f) {
    unsigned u = __float_as_uint(f);
    u += 0x7fffu + ((u >> 16) & 1u);   // round-to-nearest-even
    return (unsigned short)(u >> 16);
}
__device__ __forceinline__ float bf16tof(unsigned short h) {
    return __uint_as_float((unsigned)h << 16);
}
__device__ __forceinline__ unsigned pack2(float a, float b) {
    return (unsigned)bf16r(a) | ((unsigned)bf16r(b) << 16);
}

typedef __attribute__((ext_vector_type(8))) short short8;
typedef __attribute__((ext_vector_type(4))) float float4v;

// ---------------------------------------------------------------------------
// K0: build DFT-w twiddle table E (bf16 hi + lo) in workspace.
// E[col][w]: col 0..31 -> cos(2pi*col*w/256); col 32..63 -> -sin(2pi*(col-32)*w/256)
// Layout: 4 chunks of 64 w each; per chunk: hi[64][72] then lo[64][72] bf16
// (pitch 72 = 9x16B granules -> bank-balanced b128 reads in k_dftw).
// Lives at ws + 8388608 floats (xfr region; overwritten later by k_dfth - OK).
// ---------------------------------------------------------------------------
__global__ __launch_bounds__(256) void k_twiddle(float* __restrict__ ws) {
    unsigned short* E = (unsigned short*)(ws + 8388608);
    int idx0 = blockIdx.x * 256 + threadIdx.x;
    for (int idx = idx0; idx < 4 * 64 * 72; idx += 16 * 256) {
        int c = idx / 4608;
        int rem = idx - c * 4608;
        int col = rem / 72;
        int wp = rem - col * 72;
        unsigned short hi = 0, lo = 0;
        if (wp < 64) {
            int w = c * 64 + wp;
            int ky = col & 31;
            int prod = (ky * w) & 255;
            float s, cc;
            __sincosf(PI2_256 * (float)prod, &s, &cc);
            float val = (col < 32) ? cc : -s;
            hi = bf16r(val);
            lo = bf16r(val - bf16tof(hi));
        }
        E[c * 9216 + col * 72 + wp] = hi;
        E[c * 9216 + 4608 + col * 72 + wp] = lo;
    }
}

// ---------------------------------------------------------------------------
// K1 (MFMA): A[bc][h][ky] = sum_w x[bc][h][w] * e^{-2pi i ky w/256}, ky=0..31
//   GEMM per block: D[64 m x 128 n] = E[64 x 256] * X^T, n = h rows.
//   A-operand = E (m = E col: 0..31 Re, 32..63 Im), B-operand = X rows (k = w).
//   hi/lo bf16 split on both operands; fp32 accumulation.
// ---------------------------------------------------------------------------
__global__ __launch_bounds__(256) void k_dftw(const float* __restrict__ x,
                                              const float* __restrict__ Ews,
                                              float* __restrict__ Ar,
                                              float* __restrict__ Ai) {
    __shared__ __align__(16) unsigned char smem[55296];
    unsigned short* Xhi = (unsigned short*)smem;              // [128][72] bf16
    unsigned short* Xlo = (unsigned short*)(smem + 18432);    // [128][72]
    unsigned short* Ehi = (unsigned short*)(smem + 36864);    // [64][72], Elo at +4608
    float* obuf = (float*)smem;                               // [128][68] epilogue reuse

    int t = threadIdx.x;
    int bc = blockIdx.x >> 1;
    int h0 = (blockIdx.x & 1) << 7;
    int lane = t & 63, wid = t >> 6;
    int quad = lane >> 4, col = lane & 15;

    const uint4* Ews4 = (const uint4*)Ews;

    float4v zero = {0.f, 0.f, 0.f, 0.f};
    float4v acc[4][2];
#pragma unroll
    for (int m = 0; m < 4; ++m) {
        acc[m][0] = zero;
        acc[m][1] = zero;
    }

    for (int c = 0; c < 4; ++c) {
        // ---- stage X chunk [128 h][64 w] -> bf16 hi/lo, pitch 72 ----
        const float* xrow = x + ((size_t)bc * 256 + h0) * 256 + c * 64;
#pragma unroll
        for (int it = 0; it < 8; ++it) {
            int l = it * 256 + t;
            int r = l >> 4, f4 = l & 15;
            float4 v = *(const float4*)(xrow + (size_t)r * 256 + f4 * 4);
            unsigned short hx = bf16r(v.x), hy = bf16r(v.y);
            unsigned short hz = bf16r(v.z), hw = bf16r(v.w);
            unsigned hi0 = (unsigned)hx | ((unsigned)hy << 16);
            unsigned hi1 = (unsigned)hz | ((unsigned)hw << 16);
            unsigned lo0 = (unsigned)bf16r(v.x - bf16tof(hx)) |
                           ((unsigned)bf16r(v.y - bf16tof(hy)) << 16);
            unsigned lo1 = (unsigned)bf16r(v.z - bf16tof(hz)) |
                           ((unsigned)bf16r(v.w - bf16tof(hw)) << 16);
            int o = r * 72 + f4 * 4;
            *(uint2*)&Xhi[o] = make_uint2(hi0, hi1);
            *(uint2*)&Xlo[o] = make_uint2(lo0, lo1);
        }
        // ---- stage E chunk (hi+lo image, 1152 x 16B) ----
        for (int g = t; g < 1152; g += 256)
            ((uint4*)(smem + 36864))[g] = Ews4[c * 1152 + g];
        __syncthreads();

        // ---- MFMA: 2 K-steps of 32 per chunk ----
#pragma unroll
        for (int ks = 0; ks < 2; ++ks) {
            int ko = quad * 8 + ks * 32;
            short8 ah[4], al[4], bh[2], bl[2];
#pragma unroll
            for (int m = 0; m < 4; ++m) {
                int ro = (m * 16 + col) * 72 + ko;
                ah[m] = *(const short8*)&Ehi[ro];
                al[m] = *(const short8*)&Ehi[4608 + ro];
            }
#pragma unroll
            for (int n = 0; n < 2; ++n) {
                int hr = ((wid * 2 + n) * 16 + col) * 72 + ko;
                bh[n] = *(const short8*)&Xhi[hr];
                bl[n] = *(const short8*)&Xlo[hr];
            }
#pragma unroll
            for (int m = 0; m < 4; ++m) {
#pragma unroll
                for (int n = 0; n < 2; ++n) {
                    acc[m][n] = __builtin_amdgcn_mfma_f32_16x16x32_bf16(ah[m], bh[n], acc[m][n], 0, 0, 0);
                    acc[m][n] = __builtin_amdgcn_mfma_f32_16x16x32_bf16(ah[m], bl[n], acc[m][n], 0, 0, 0);
                    acc[m][n] = __builtin_amdgcn_mfma_f32_16x16x32_bf16(al[m], bh[n], acc[m][n], 0, 0, 0);
                }
            }
        }
        __syncthreads();
    }

    // ---- epilogue: D[m][n] -> obuf[h_local][m] (transpose), then coalesced store ----
#pragma unroll
    for (int m = 0; m < 4; ++m) {
#pragma unroll
        for (int n = 0; n < 2; ++n) {
            int hl = (wid * 2 + n) * 16 + col;
            *(float4v*)&obuf[hl * 68 + m * 16 + quad * 4] = acc[m][n];
        }
    }
    __syncthreads();
#pragma unroll
    for (int it = 0; it < 8; ++it) {
        int l = it * 256 + t;
        int hh = l >> 4, f = l & 15;
        float4 v = *(float4*)&obuf[hh * 68 + f * 4];
        size_t g = (size_t)bc * 8192 + (size_t)(h0 + hh) * 32;
        if (f < 8) *(float4*)(Ar + g + f * 4) = v;
        else       *(float4*)(Ai + g + (f - 8) * 4) = v;
    }
}

// ---------------------------------------------------------------------------
// K2: xf[bc][kxi][ky] = sum_h A[bc][h][ky] * e^{-2pi i kx h/256}
//     kxi 0..31 -> kx=kxi (top), kxi 32..63 -> kx=kxi+192 (rows 224..255)
// ---------------------------------------------------------------------------
__global__ __launch_bounds__(256) void k_dfth(const float* __restrict__ Ar,
                                              const float* __restrict__ Ai,
                                              float* __restrict__ xfr,
                                              float* __restrict__ xfi) {
    __shared__ __align__(16) float asr[256 * 32];     // [h][ky]
    __shared__ __align__(16) float asi[256 * 32];
    __shared__ __align__(16) float ob[64 * 33];       // [kxi][ky] staging
    int t = threadIdx.x;
    int bc = blockIdx.x;
    const float4* sr = (const float4*)(Ar + (size_t)bc * 8192);
    const float4* si = (const float4*)(Ai + (size_t)bc * 8192);
#pragma unroll
    for (int it = 0; it < 8; ++it) {
        ((float4*)asr)[it * 256 + t] = sr[it * 256 + t];
        ((float4*)asi)[it * 256 + t] = si[it * 256 + t];
    }
    __syncthreads();

    int kxi = t & 63, kg = t >> 6;   // kg is wave-uniform
    int kx = (kxi < 32) ? kxi : kxi + 192;
    float c1, s1;
    __sincosf(PI2_256 * (float)kx, &s1, &c1);
    float c = 1.f, s = 0.f;
    float xr[8] = {0, 0, 0, 0, 0, 0, 0, 0};
    float xi_[8] = {0, 0, 0, 0, 0, 0, 0, 0};
    for (int h = 0; h < 256; ++h) {
        float4 a0 = *(float4*)&asr[h * 32 + kg * 8];
        float4 a1 = *(float4*)&asr[h * 32 + kg * 8 + 4];
        float4 b0 = *(float4*)&asi[h * 32 + kg * 8];
        float4 b1 = *(float4*)&asi[h * 32 + kg * 8 + 4];
        float arv[8] = {a0.x, a0.y, a0.z, a0.w, a1.x, a1.y, a1.z, a1.w};
        float aiv[8] = {b0.x, b0.y, b0.z, b0.w, b1.x, b1.y, b1.z, b1.w};
#pragma unroll
        for (int j = 0; j < 8; ++j) {
            xr[j] += arv[j] * c + aiv[j] * s;   // A * e^{-i t}: (ar+i ai)(c - i s)
            xi_[j] += aiv[j] * c - arv[j] * s;
        }
        float nc = c * c1 - s * s1;
        s = s * c1 + c * s1;
        c = nc;
    }
#pragma unroll
    for (int j = 0; j < 8; ++j) ob[kxi * 33 + kg * 8 + j] = xr[j];
    __syncthreads();
#pragma unroll
    for (int it = 0; it < 8; ++it) {
        int l = it * 256 + t;
        xfr[(size_t)bc * 2048 + l] = ob[(l >> 5) * 33 + (l & 31)];
    }
    __syncthreads();
#pragma unroll
    for (int j = 0; j < 8; ++j) ob[kxi * 33 + kg * 8 + j] = xi_[j];
    __syncthreads();
#pragma unroll
    for (int it = 0; it < 8; ++it) {
        int l = it * 256 + t;
        xfi[(size_t)bc * 2048 + l] = ob[(l >> 5) * 33 + (l & 31)];
    }
}

// ---------------------------------------------------------------------------
// K3: in-place per-mode complex channel mix (batch-split across blocks):
//     of[b,o,kxi,ky] = sum_i xf[b,i,kxi,ky] * (wr + i wi)[i,o, kxi%32, ky]
// ---------------------------------------------------------------------------
__global__ __launch_bounds__(256) void k_mix(float* __restrict__ xfr,
                                             float* __restrict__ xfi,
                                             const float* __restrict__ w1r,
                                             const float* __restrict__ w1i,
                                             const float* __restrict__ w2r,
                                             const float* __restrict__ w2i) {
    __shared__ float wr[32 * 32 * 8];   // [i][o][q]
    __shared__ float wi[32 * 32 * 8];
    __shared__ float xsr[32 * 8];       // [i][q]
    __shared__ float xsi[32 * 8];
    int t = threadIdx.x;
    int kxi = (blockIdx.x >> 2) & 63;
    int ky0 = (blockIdx.x & 3) * 8;
    int b0 = (blockIdx.x >> 8) * 4;     // 4 batches per block
    const float* Wr = (kxi < 32) ? w1r : w2r;
    const float* Wi = (kxi < 32) ? w1i : w2i;
    int m1 = kxi & 31;
#pragma unroll
    for (int it = 0; it < 32; ++it) {
        int l = it * 256 + t;                 // l = i*256 + o*8 + q
        int i = l >> 8, o = (l >> 3) & 31, q = l & 7;
        size_t g = (size_t)i * 32768 + (size_t)o * 1024 + m1 * 32 + ky0 + q;
        wr[l] = Wr[g];
        wi[l] = Wi[g];
    }
    __syncthreads();

    int o = t >> 3, q = t & 7;
    for (int b = b0; b < b0 + 4; ++b) {
        __syncthreads();
        {
            int i = t >> 3, qq = t & 7;
            size_t g = ((size_t)(b * 32 + i)) * 2048 + (size_t)kxi * 32 + ky0 + qq;
            xsr[t] = xfr[g];
            xsi[t] = xfi[g];
        }
        __syncthreads();
        float accr = 0.f, acci = 0.f;
#pragma unroll
        for (int i = 0; i < 32; ++i) {
            float xr = xsr[i * 8 + q], xim = xsi[i * 8 + q];
            float wrv = wr[i * 256 + o * 8 + q], wiv = wi[i * 256 + o * 8 + q];
            accr += xr * wrv - xim * wiv;
            acci += xr * wiv + xim * wrv;
        }
        size_t g = ((size_t)(b * 32 + o)) * 2048 + (size_t)kxi * 32 + ky0 + q;
        xfr[g] = accr;   // safe: only this block touches this (b,kxi,ky) slice
        xfi[g] = acci;
    }
}

// ---------------------------------------------------------------------------
// K4: T[bo][h][2*ky] = scale * sum_kxi of[bo,kxi,ky] * e^{+2pi i kx h/256}
//     scale = (ky==0 ? 1 : 2) / 65536  (irfft Hermitian coeff + 1/(H*W))
// ---------------------------------------------------------------------------
__global__ __launch_bounds__(256) void k_idfth(const float* __restrict__ ofr,
                                               const float* __restrict__ ofi,
                                               float* __restrict__ T) {
    __shared__ __align__(16) float osr[64 * 32];   // [kxi][ky]
    __shared__ __align__(16) float osi[64 * 32];
    __shared__ __align__(16) float obT[64 * 64];   // [h_local][2ky interleaved]
    int t = threadIdx.x;
    int bo = blockIdx.x;
#pragma unroll
    for (int it = 0; it < 2; ++it) {
        ((float4*)osr)[it * 256 + t] = ((const float4*)(ofr + (size_t)bo * 2048))[it * 256 + t];
        ((float4*)osi)[it * 256 + t] = ((const float4*)(ofi + (size_t)bo * 2048))[it * 256 + t];
    }
    __syncthreads();

    int ky = t & 31, hg = t >> 5;
    float sc = ((ky == 0) ? 1.f : 2.f) * (1.f / 65536.f);
    for (int hc = 0; hc < 4; ++hc) {
        float tr[8] = {0, 0, 0, 0, 0, 0, 0, 0}, ti[8] = {0, 0, 0, 0, 0, 0, 0, 0};
        float cc[8], ss[8], ca[8], sa[8];
#pragma unroll
        for (int j = 0; j < 8; ++j) {
            int h = hc * 64 + hg * 8 + j;
            __sincosf(PI2_256 * (float)h, &sa[j], &ca[j]);  // step e^{+i 2pi h/256}
            cc[j] = 1.f;
            ss[j] = 0.f;
        }
        for (int kxi = 0; kxi < 32; ++kxi) {   // kx = kxi
            float orv = osr[kxi * 32 + ky], oiv = osi[kxi * 32 + ky];
#pragma unroll
            for (int j = 0; j < 8; ++j) {
                tr[j] += orv * cc[j] - oiv * ss[j];
                ti[j] += orv * ss[j] + oiv * cc[j];
                float nc = cc[j] * ca[j] - ss[j] * sa[j];
                ss[j] = ss[j] * ca[j] + cc[j] * sa[j];
                cc[j] = nc;
            }
        }
#pragma unroll
        for (int j = 0; j < 8; ++j) {          // reinit at kx=224
            int h = hc * 64 + hg * 8 + j;
            int m = (224 * h) & 255;
            __sincosf(PI2_256 * (float)m, &ss[j], &cc[j]);
        }
        for (int kxi = 32; kxi < 64; ++kxi) {  // kx = kxi+192
            float orv = osr[kxi * 32 + ky], oiv = osi[kxi * 32 + ky];
#pragma unroll
            for (int j = 0; j < 8; ++j) {
                tr[j] += orv * cc[j] - oiv * ss[j];
                ti[j] += orv * ss[j] + oiv * cc[j];
                float nc = cc[j] * ca[j] - ss[j] * sa[j];
                ss[j] = ss[j] * ca[j] + cc[j] * sa[j];
                cc[j] = nc;
            }
        }
        __syncthreads();  // previous hc's copy-out fully read obT
#pragma unroll
        for (int j = 0; j < 8; ++j) {
            int hl = hg * 8 + j;
            obT[hl * 64 + 2 * ky] = tr[j] * sc;
            obT[hl * 64 + 2 * ky + 1] = ti[j] * sc;
        }
        __syncthreads();
        float* dst = T + (size_t)bo * 16384 + hc * 4096;
#pragma unroll
        for (int it = 0; it < 4; ++it)
            ((float4*)dst)[it * 256 + t] = ((float4*)obT)[it * 256 + t];
    }
}

// ---------------------------------------------------------------------------
// K5 (MFMA): per (b,h,w-half): D[32 o x 128 w] = A[32 x 160] * B[160 x 128]
//   A = [ cw (96) | Tr (32) | Ti (32) ]   (bf16, pre-packed in lane order)
//   B = [ x; dh; dw (96) | cos (32) | -sin (32) ]  rows, built in LDS bf16.
//   FP32 accumulation via v_mfma_f32_16x16x32_bf16.
// ---------------------------------------------------------------------------
#define BT_PITCH 164   // bf16 elements per Bt row (41 dwords: odd mod 32 -> 2-way max)

__global__ __launch_bounds__(256) void k_final(const float* __restrict__ x,
                                               const float* __restrict__ cw,
                                               const float* __restrict__ cb,
                                               const float* __restrict__ T,
                                               float* __restrict__ out) {
    __shared__ unsigned short Bt[128 * BT_PITCH];        // [n][k] 41,984 B
    __shared__ __align__(16) unsigned short Afr[5 * 2 * 64 * 8];  // [ks][mt][lane][8] 10,240 B

    int t = threadIdx.x;
    int b = blockIdx.x >> 9;
    int h = (blockIdx.x >> 1) & 255;
    int w0 = (blockIdx.x & 1) << 7;

    // ---- stage B: feats rows (k=0..95) ----
    {
        int nn = t & 127, half = t >> 7;       // half picks i-range 0..15 / 16..31
        int w = w0 + nn;
        int hs = (h < 255) ? h + 1 : h;
        int we = (w < 255) ? 1 : 0;
#pragma unroll
        for (int ip = 0; ip < 8; ++ip) {
            int i0 = half * 16 + ip * 2;
            const float* x0 = x + ((size_t)(b * 32 + i0)) * 65536;
            const float* x1 = x0 + 65536;
            float c0 = x0[h * 256 + w];
            float s0 = x0[hs * 256 + w];
            float e0 = x0[h * 256 + w + we];
            float c1 = x1[h * 256 + w];
            float s1 = x1[hs * 256 + w];
            float e1 = x1[h * 256 + w + we];
            *(unsigned*)&Bt[nn * BT_PITCH + i0]      = pack2(c0, c1);
            *(unsigned*)&Bt[nn * BT_PITCH + 32 + i0] = pack2(s0 - c0, s1 - c1);
            *(unsigned*)&Bt[nn * BT_PITCH + 64 + i0] = pack2(e0 - c0, e1 - c1);
        }
    }
    // ---- stage B: twiddle rows (k=96..159): cos(2pi kk w/256), -sin(...) ----
    {
        int nn = t & 127, half = t >> 7;
        int w = w0 + nn;
        float c1, s1;
        __sincosf(PI2_256 * (float)w, &s1, &c1);
        int kk0 = half * 16;
        float c, s;
        __sincosf(PI2_256 * (float)((w * kk0) & 255), &s, &c);
#pragma unroll
        for (int kp = 0; kp < 8; ++kp) {
            int kk = kk0 + kp * 2;
            float ca = c, sa = s;
            float nc = c * c1 - s * s1; s = s * c1 + c * s1; c = nc;   // kk+1
            float cbv = c, sbv = s;
            nc = c * c1 - s * s1; s = s * c1 + c * s1; c = nc;         // kk+2
            *(unsigned*)&Bt[nn * BT_PITCH + 96 + kk]  = pack2(ca, cbv);
            *(unsigned*)&Bt[nn * BT_PITCH + 128 + kk] = pack2(-sa, -sbv);
        }
    }
    // ---- stage A fragments: lane-order pack of [cw | Tr | Ti] ----
    for (int slot = t; slot < 640; slot += 256) {
        int ks = slot >> 7;            // 0..4
        int mt = (slot >> 6) & 1;
        int lane = slot & 63;
        int m = (lane & 15) + mt * 16; // output channel o
        int kb = ks * 32 + (lane >> 4) * 8;
        float v[8];
        if (ks < 3) {
#pragma unroll
            for (int j = 0; j < 8; ++j) v[j] = cw[m * 96 + kb + j];
        } else {
            const float* tp = T + ((size_t)(b * 32 + m)) * 16384 + (size_t)h * 64;
            int kkb = kb - (ks == 3 ? 96 : 128);
            int im = (ks == 3) ? 0 : 1;
#pragma unroll
            for (int j = 0; j < 8; ++j) v[j] = tp[2 * (kkb + j) + im];
        }
        uint4 pk;
        pk.x = pack2(v[0], v[1]); pk.y = pack2(v[2], v[3]);
        pk.z = pack2(v[4], v[5]); pk.w = pack2(v[6], v[7]);
        *(uint4*)&Afr[((ks * 2 + mt) * 64 + lane) * 8] = pk;
    }
    __syncthreads();

    // ---- MFMA K-loop ----
    int lane = t & 63, wid = t >> 6;
    int quad = lane >> 4, col = lane & 15;
    float4v zero = {0.f, 0.f, 0.f, 0.f};
    float4v acc[2][2];
    acc[0][0] = zero; acc[0][1] = zero; acc[1][0] = zero; acc[1][1] = zero;

#pragma unroll
    for (int ks = 0; ks < 5; ++ks) {
        short8 a0 = *(const short8*)&Afr[((ks * 2 + 0) * 64 + lane) * 8];
        short8 a1 = *(const short8*)&Afr[((ks * 2 + 1) * 64 + lane) * 8];
        int kb = ks * 32 + quad * 8;
        union { unsigned long long q[2]; short8 v; } ub0, ub1;
        const unsigned short* r0 = &Bt[(wid * 32 + col) * BT_PITCH + kb];
        const unsigned short* r1 = &Bt[(wid * 32 + 16 + col) * BT_PITCH + kb];
        ub0.q[0] = *(const unsigned long long*)(r0);
        ub0.q[1] = *(const unsigned long long*)(r0 + 4);
        ub1.q[0] = *(const unsigned long long*)(r1);
        ub1.q[1] = *(const unsigned long long*)(r1 + 4);
        acc[0][0] = __builtin_amdgcn_mfma_f32_16x16x32_bf16(a0, ub0.v, acc[0][0], 0, 0, 0);
        acc[1][0] = __builtin_amdgcn_mfma_f32_16x16x32_bf16(a1, ub0.v, acc[1][0], 0, 0, 0);
        acc[0][1] = __builtin_amdgcn_mfma_f32_16x16x32_bf16(a0, ub1.v, acc[0][1], 0, 0, 0);
        acc[1][1] = __builtin_amdgcn_mfma_f32_16x16x32_bf16(a1, ub1.v, acc[1][1], 0, 0, 0);
    }

    // ---- epilogue: C/D layout col=lane&15, row=quad*4+reg; add bias ----
#pragma unroll
    for (int mt = 0; mt < 2; ++mt) {
#pragma unroll
        for (int nt = 0; nt < 2; ++nt) {
#pragma unroll
            for (int reg = 0; reg < 4; ++reg) {
                int o = mt * 16 + quad * 4 + reg;
                int w = w0 + wid * 32 + nt * 16 + col;
                out[(((size_t)(b * 32 + o)) * 256 + h) * 256 + w] = acc[mt][nt][reg] + cb[o];
            }
        }
    }
}

// ---------------------------------------------------------------------------
extern "C" void kernel_launch(void* const* d_in, const int* in_sizes, int n_in,
                              void* d_out, int out_size, void* d_ws, size_t ws_size,
                              hipStream_t stream) {
    const float* x = (const float*)d_in[0];
    const float* conv_w = (const float*)d_in[1];
    const float* conv_b = (const float*)d_in[2];
    const float* w1r = (const float*)d_in[3];
    const float* w1i = (const float*)d_in[4];
    const float* w2r = (const float*)d_in[5];
    const float* w2i = (const float*)d_in[6];
    float* out = (float*)d_out;

    float* ws = (float*)d_ws;
    float* Ar = ws;                    // 4,194,304 floats: A real  [bc][h][ky]
    float* Ai = ws + 4194304;          // 4,194,304 floats: A imag
    float* Tbuf = ws;                  // 8,388,608 floats: T [bo][h][2ky] (reuses A region)
    float* xfr = ws + 8388608;         // 1,048,576 floats: xf/of real [bc][kxi][ky]
    float* xfi = ws + 9437184;         // 1,048,576 floats: xf/of imag
    const float* Ews = ws + 8388608;   // 73,728 B twiddle table (xfr region; k_dfth
                                       // overwrites it AFTER k_dftw has consumed it)
    // total workspace: 10,485,760 floats = 40 MiB

    k_twiddle<<<16, 256, 0, stream>>>(ws);
    k_dftw<<<1024, 256, 0, stream>>>(x, Ews, Ar, Ai);
    k_dfth<<<512, 256, 0, stream>>>(Ar, Ai, xfr, xfi);
    k_mix<<<1024, 256, 0, stream>>>(xfr, xfi, w1r, w1i, w2r, w2i);
    k_idfth<<<512, 256, 0, stream>>>(xfr, xfi, Tbuf);
    k_final<<<8192, 256, 0, stream>>>(x, conv_w, conv_b, Tbuf, out);
}

// Round 3
// 431.846 us; speedup vs baseline: 1.3510x; 1.1913x over previous
//
#include <hip/hip_runtime.h>

// Combi layer: diff-stencil 1x1 conv + truncated spectral conv.
// B=16, C=32 (in=out), H=W=256, modes M1=M2=32.
// Spectral path via partial DFTs (only 64 kx x 32 ky modes needed).
// R1: k_dftw as bf16 MFMA GEMM with hi/lo split precision.
// R2: k_dfth and k_idfth converted the same way (all three DFT stages now MFMA).
// R3: resubmit of R2 (container infra failure; source re-audited - no changes).

#define PI2_256 0.02454369260617026f   // 2*pi/256

__device__ __forceinline__ unsigned short bf16r(float f) {
    unsigned u = __float_as_uint(f);
    u += 0x7fffu + ((u >> 16) & 1u);   // round-to-nearest-even
    return (unsigned short)(u >> 16);
}
__device__ __forceinline__ float bf16tof(unsigned short h) {
    return __uint_as_float((unsigned)h << 16);
}
__device__ __forceinline__ unsigned pack2(float a, float b) {
    return (unsigned)bf16r(a) | ((unsigned)bf16r(b) << 16);
}

typedef __attribute__((ext_vector_type(8))) short short8;
typedef __attribute__((ext_vector_type(4))) float float4v;

// ---------------------------------------------------------------------------
// K0: build DFT-w twiddle table E (bf16 hi + lo) in workspace.
// E[col][w]: col 0..31 -> cos(2pi*col*w/256); col 32..63 -> -sin(2pi*(col-32)*w/256)
// Layout: 4 chunks of 64 w each; per chunk: hi[64][72] then lo[64][72] bf16.
// Lives at ws + 8388608 floats (xfr region; overwritten later by k_dfth - OK).
// ---------------------------------------------------------------------------
__global__ __launch_bounds__(256) void k_twiddle(float* __restrict__ ws) {
    unsigned short* E = (unsigned short*)(ws + 8388608);
    int idx0 = blockIdx.x * 256 + threadIdx.x;
    for (int idx = idx0; idx < 4 * 64 * 72; idx += 16 * 256) {
        int c = idx / 4608;
        int rem = idx - c * 4608;
        int col = rem / 72;
        int wp = rem - col * 72;
        unsigned short hi = 0, lo = 0;
        if (wp < 64) {
            int w = c * 64 + wp;
            int ky = col & 31;
            int prod = (ky * w) & 255;
            float s, cc;
            __sincosf(PI2_256 * (float)prod, &s, &cc);
            float val = (col < 32) ? cc : -s;
            hi = bf16r(val);
            lo = bf16r(val - bf16tof(hi));
        }
        E[c * 9216 + col * 72 + wp] = hi;
        E[c * 9216 + 4608 + col * 72 + wp] = lo;
    }
}

// ---------------------------------------------------------------------------
// K1 (MFMA): A[bc][h][ky] = sum_w x[bc][h][w] * e^{-2pi i ky w/256}, ky=0..31
// ---------------------------------------------------------------------------
__global__ __launch_bounds__(256) void k_dftw(const float* __restrict__ x,
                                              const float* __restrict__ Ews,
                                              float* __restrict__ Ar,
                                              float* __restrict__ Ai) {
    __shared__ __align__(16) unsigned char smem[55296];
    unsigned short* Xhi = (unsigned short*)smem;              // [128][72] bf16
    unsigned short* Xlo = (unsigned short*)(smem + 18432);    // [128][72]
    unsigned short* Ehi = (unsigned short*)(smem + 36864);    // [64][72], Elo at +4608
    float* obuf = (float*)smem;                               // [128][68] epilogue reuse

    int t = threadIdx.x;
    int bc = blockIdx.x >> 1;
    int h0 = (blockIdx.x & 1) << 7;
    int lane = t & 63, wid = t >> 6;
    int quad = lane >> 4, col = lane & 15;

    const uint4* Ews4 = (const uint4*)Ews;

    float4v zero = {0.f, 0.f, 0.f, 0.f};
    float4v acc[4][2];
#pragma unroll
    for (int m = 0; m < 4; ++m) {
        acc[m][0] = zero;
        acc[m][1] = zero;
    }

    for (int c = 0; c < 4; ++c) {
        // ---- stage X chunk [128 h][64 w] -> bf16 hi/lo, pitch 72 ----
        const float* xrow = x + ((size_t)bc * 256 + h0) * 256 + c * 64;
#pragma unroll
        for (int it = 0; it < 8; ++it) {
            int l = it * 256 + t;
            int r = l >> 4, f4 = l & 15;
            float4 v = *(const float4*)(xrow + (size_t)r * 256 + f4 * 4);
            unsigned short hx = bf16r(v.x), hy = bf16r(v.y);
            unsigned short hz = bf16r(v.z), hw = bf16r(v.w);
            unsigned hi0 = (unsigned)hx | ((unsigned)hy << 16);
            unsigned hi1 = (unsigned)hz | ((unsigned)hw << 16);
            unsigned lo0 = (unsigned)bf16r(v.x - bf16tof(hx)) |
                           ((unsigned)bf16r(v.y - bf16tof(hy)) << 16);
            unsigned lo1 = (unsigned)bf16r(v.z - bf16tof(hz)) |
                           ((unsigned)bf16r(v.w - bf16tof(hw)) << 16);
            int o = r * 72 + f4 * 4;
            *(uint2*)&Xhi[o] = make_uint2(hi0, hi1);
            *(uint2*)&Xlo[o] = make_uint2(lo0, lo1);
        }
        // ---- stage E chunk (hi+lo image, 1152 x 16B) ----
        for (int g = t; g < 1152; g += 256)
            ((uint4*)(smem + 36864))[g] = Ews4[c * 1152 + g];
        __syncthreads();

        // ---- MFMA: 2 K-steps of 32 per chunk ----
#pragma unroll
        for (int ks = 0; ks < 2; ++ks) {
            int ko = quad * 8 + ks * 32;
            short8 ah[4], al[4], bh[2], bl[2];
#pragma unroll
            for (int m = 0; m < 4; ++m) {
                int ro = (m * 16 + col) * 72 + ko;
                ah[m] = *(const short8*)&Ehi[ro];
                al[m] = *(const short8*)&Ehi[4608 + ro];
            }
#pragma unroll
            for (int n = 0; n < 2; ++n) {
                int hr = ((wid * 2 + n) * 16 + col) * 72 + ko;
                bh[n] = *(const short8*)&Xhi[hr];
                bl[n] = *(const short8*)&Xlo[hr];
            }
#pragma unroll
            for (int m = 0; m < 4; ++m) {
#pragma unroll
                for (int n = 0; n < 2; ++n) {
                    acc[m][n] = __builtin_amdgcn_mfma_f32_16x16x32_bf16(ah[m], bh[n], acc[m][n], 0, 0, 0);
                    acc[m][n] = __builtin_amdgcn_mfma_f32_16x16x32_bf16(ah[m], bl[n], acc[m][n], 0, 0, 0);
                    acc[m][n] = __builtin_amdgcn_mfma_f32_16x16x32_bf16(al[m], bh[n], acc[m][n], 0, 0, 0);
                }
            }
        }
        __syncthreads();
    }

    // ---- epilogue: D[m][n] -> obuf[h_local][m] (transpose), then coalesced store ----
#pragma unroll
    for (int m = 0; m < 4; ++m) {
#pragma unroll
        for (int n = 0; n < 2; ++n) {
            int hl = (wid * 2 + n) * 16 + col;
            *(float4v*)&obuf[hl * 68 + m * 16 + quad * 4] = acc[m][n];
        }
    }
    __syncthreads();
#pragma unroll
    for (int it = 0; it < 8; ++it) {
        int l = it * 256 + t;
        int hh = l >> 4, f = l & 15;
        float4 v = *(float4*)&obuf[hh * 68 + f * 4];
        size_t g = (size_t)bc * 8192 + (size_t)(h0 + hh) * 32;
        if (f < 8) *(float4*)(Ar + g + f * 4) = v;
        else       *(float4*)(Ai + g + (f - 8) * 4) = v;
    }
}

// ---------------------------------------------------------------------------
// K2 (MFMA): xf[bc][kxi][ky] = sum_h A[bc][h][ky] * e^{-2pi i kx h/256}
//   GEMM per bc: D[128 m][32 n], m = 2*kxi + (re/im), n = ky, K = 512
//   (k = 2h + {Ar,Ai}).  F2[2kxi][2h,2h+1] = (cos,sin); F2[2kxi+1] = (-sin,cos).
//   B2[ky][2h,2h+1] = (Ar[h][ky], Ai[h][ky]).  hi/lo bf16 split, K chunked by 64.
// ---------------------------------------------------------------------------
#define DF_PITCH 72   // shorts/row = 36 dwords == 4 mod 32 -> uniform bank spread

__global__ __launch_bounds__(256) void k_dfth(const float* __restrict__ Ar,
                                              const float* __restrict__ Ai,
                                              float* __restrict__ xfr,
                                              float* __restrict__ xfi) {
    __shared__ __align__(16) unsigned short F2h[128 * DF_PITCH];
    __shared__ __align__(16) unsigned short F2l[128 * DF_PITCH];
    __shared__ __align__(16) unsigned short B2h[32 * DF_PITCH];
    __shared__ __align__(16) unsigned short B2l[32 * DF_PITCH];

    int t = threadIdx.x;
    int bc = blockIdx.x;
    int lane = t & 63, wid = t >> 6;
    int quad = lane >> 4, col = lane & 15;

    // twiddle-builder identity: row m = t&127, k-half = t>>7
    int m = t & 127;
    int kxi = m >> 1;
    int kx = (kxi < 32) ? kxi : kxi + 192;
    int neg = m & 1;
    int khalf = t >> 7;
    float c1, s1;
    __sincosf(PI2_256 * (float)kx, &s1, &c1);   // per-h step e^{+i 2pi kx/256}

    float4v zero = {0.f, 0.f, 0.f, 0.f};
    float4v acc[2][2];
    acc[0][0] = zero; acc[0][1] = zero; acc[1][0] = zero; acc[1][1] = zero;

    for (int hc = 0; hc < 8; ++hc) {
        // ---- F2 tile: rows m=0..127, cols k = 2h'+cs, h = hc*32 + h' ----
        {
            int h0 = hc * 32 + khalf * 16;
            float c, s;
            __sincosf(PI2_256 * (float)((kx * h0) & 255), &s, &c);
#pragma unroll
            for (int j = 0; j < 16; ++j) {
                int kk = 2 * (khalf * 16 + j);
                float ch = bf16tof(bf16r(c)), sh = bf16tof(bf16r(s));
                float cl = c - ch, sl = s - sh;
                unsigned hiw, low;
                if (neg == 0) { hiw = pack2(c, s);  low = pack2(cl, sl); }
                else          { hiw = pack2(-s, c); low = pack2(-sl, cl); }
                *(unsigned*)&F2h[m * DF_PITCH + kk] = hiw;
                *(unsigned*)&F2l[m * DF_PITCH + kk] = low;
                float nc = c * c1 - s * s1;
                s = s * c1 + c * s1;
                c = nc;
            }
        }
        // ---- B2 tile: rows ky=0..31, cols k = 2h'+{Ar,Ai} ----
        {
            int hl = t >> 3;               // 0..31
            int ky0 = (t & 7) * 4;
            const float* pr = Ar + (size_t)bc * 8192 + (size_t)(hc * 32 + hl) * 32 + ky0;
            const float* pi = Ai + (size_t)bc * 8192 + (size_t)(hc * 32 + hl) * 32 + ky0;
            float4 vr = *(const float4*)pr;
            float4 vi = *(const float4*)pi;
            float fr[4] = {vr.x, vr.y, vr.z, vr.w};
            float fi[4] = {vi.x, vi.y, vi.z, vi.w};
#pragma unroll
            for (int q = 0; q < 4; ++q) {
                float ar = fr[q], ai = fi[q];
                float arh = bf16tof(bf16r(ar)), aih = bf16tof(bf16r(ai));
                *(unsigned*)&B2h[(ky0 + q) * DF_PITCH + 2 * hl] = pack2(ar, ai);
                *(unsigned*)&B2l[(ky0 + q) * DF_PITCH + 2 * hl] = pack2(ar - arh, ai - aih);
            }
        }
        __syncthreads();
        // ---- MFMA: 2 K-steps of 32 ----
#pragma unroll
        for (int ks = 0; ks < 2; ++ks) {
            int ko = ks * 32 + quad * 8;
            short8 ah[2], al[2], bh[2], bl[2];
#pragma unroll
            for (int mi = 0; mi < 2; ++mi) {
                int ro = ((wid * 2 + mi) * 16 + col) * DF_PITCH + ko;
                ah[mi] = *(const short8*)&F2h[ro];
                al[mi] = *(const short8*)&F2l[ro];
            }
#pragma unroll
            for (int ni = 0; ni < 2; ++ni) {
                int ro = (ni * 16 + col) * DF_PITCH + ko;
                bh[ni] = *(const short8*)&B2h[ro];
                bl[ni] = *(const short8*)&B2l[ro];
            }
#pragma unroll
            for (int mi = 0; mi < 2; ++mi) {
#pragma unroll
                for (int ni = 0; ni < 2; ++ni) {
                    acc[mi][ni] = __builtin_amdgcn_mfma_f32_16x16x32_bf16(ah[mi], bh[ni], acc[mi][ni], 0, 0, 0);
                    acc[mi][ni] = __builtin_amdgcn_mfma_f32_16x16x32_bf16(ah[mi], bl[ni], acc[mi][ni], 0, 0, 0);
                    acc[mi][ni] = __builtin_amdgcn_mfma_f32_16x16x32_bf16(al[mi], bh[ni], acc[mi][ni], 0, 0, 0);
                }
            }
        }
        __syncthreads();
    }
    // ---- epilogue: m = (wid*2+mi)*16+quad*4+reg -> kxi=m>>1, re/im=m&1 ----
#pragma unroll
    for (int mi = 0; mi < 2; ++mi) {
#pragma unroll
        for (int ni = 0; ni < 2; ++ni) {
#pragma unroll
            for (int reg = 0; reg < 4; ++reg) {
                int mm = (wid * 2 + mi) * 16 + quad * 4 + reg;
                size_t g = (size_t)bc * 2048 + (size_t)(mm >> 1) * 32 + ni * 16 + col;
                if (mm & 1) xfi[g] = acc[mi][ni][reg];
                else        xfr[g] = acc[mi][ni][reg];
            }
        }
    }
}

// ---------------------------------------------------------------------------
// K3: in-place per-mode complex channel mix (batch-split across blocks):
//     of[b,o,kxi,ky] = sum_i xf[b,i,kxi,ky] * (wr + i wi)[i,o, kxi%32, ky]
// ---------------------------------------------------------------------------
__global__ __launch_bounds__(256) void k_mix(float* __restrict__ xfr,
                                             float* __restrict__ xfi,
                                             const float* __restrict__ w1r,
                                             const float* __restrict__ w1i,
                                             const float* __restrict__ w2r,
                                             const float* __restrict__ w2i) {
    __shared__ float wr[32 * 32 * 8];   // [i][o][q]
    __shared__ float wi[32 * 32 * 8];
    __shared__ float xsr[32 * 8];       // [i][q]
    __shared__ float xsi[32 * 8];
    int t = threadIdx.x;
    int kxi = (blockIdx.x >> 2) & 63;
    int ky0 = (blockIdx.x & 3) * 8;
    int b0 = (blockIdx.x >> 8) * 4;     // 4 batches per block
    const float* Wr = (kxi < 32) ? w1r : w2r;
    const float* Wi = (kxi < 32) ? w1i : w2i;
    int m1 = kxi & 31;
#pragma unroll
    for (int it = 0; it < 32; ++it) {
        int l = it * 256 + t;                 // l = i*256 + o*8 + q
        int i = l >> 8, o = (l >> 3) & 31, q = l & 7;
        size_t g = (size_t)i * 32768 + (size_t)o * 1024 + m1 * 32 + ky0 + q;
        wr[l] = Wr[g];
        wi[l] = Wi[g];
    }
    __syncthreads();

    int o = t >> 3, q = t & 7;
    for (int b = b0; b < b0 + 4; ++b) {
        __syncthreads();
        {
            int i = t >> 3, qq = t & 7;
            size_t g = ((size_t)(b * 32 + i)) * 2048 + (size_t)kxi * 32 + ky0 + qq;
            xsr[t] = xfr[g];
            xsi[t] = xfi[g];
        }
        __syncthreads();
        float accr = 0.f, acci = 0.f;
#pragma unroll
        for (int i = 0; i < 32; ++i) {
            float xr = xsr[i * 8 + q], xim = xsi[i * 8 + q];
            float wrv = wr[i * 256 + o * 8 + q], wiv = wi[i * 256 + o * 8 + q];
            accr += xr * wrv - xim * wiv;
            acci += xr * wiv + xim * wrv;
        }
        size_t g = ((size_t)(b * 32 + o)) * 2048 + (size_t)kxi * 32 + ky0 + q;
        xfr[g] = accr;   // safe: only this block touches this (b,kxi,ky) slice
        xfi[g] = acci;
    }
}

// ---------------------------------------------------------------------------
// K4 (MFMA): T[bo][h][2*ky+reim] = scale * sum_kxi of[bo,kxi,ky]*e^{+2pi i kx h/256}
//   GEMM per bo: D[256 h][64 n], n = 2ky+reim, K = 128 (k = 2kxi+{cos,sin}).
//   F[h][2kxi,2kxi+1] = (cos,sin)(2pi kx h/256);
//   G[2ky][2kxi,2kxi+1] = (or,-oi)*sc; G[2ky+1][...] = (oi,or)*sc.
//   h chunked by 64 (F rebuilt per chunk); G staged once. hi/lo bf16 split.
// ---------------------------------------------------------------------------
#define IF_PITCH 136  // shorts/row = 68 dwords == 4 mod 32, rows 16B-aligned

__global__ __launch_bounds__(256) void k_idfth(const float* __restrict__ ofr,
                                               const float* __restrict__ ofi,
                                               float* __restrict__ T) {
    __shared__ __align__(16) unsigned short Fh[64 * IF_PITCH];
    __shared__ __align__(16) unsigned short Fl[64 * IF_PITCH];
    __shared__ __align__(16) unsigned short Gh[64 * IF_PITCH];
    __shared__ __align__(16) unsigned short Gl[64 * IF_PITCH];

    int t = threadIdx.x;
    int bo = blockIdx.x;
    int lane = t & 63, wid = t >> 6;
    int quad = lane >> 4, col = lane & 15;

    // ---- build G (of-derived; shared by all h-chunks) ----
    {
        int kxi = t >> 2;               // 0..63
        int ky0 = (t & 3) * 8;
        const float* pr = ofr + (size_t)bo * 2048 + (size_t)kxi * 32 + ky0;
        const float* pi = ofi + (size_t)bo * 2048 + (size_t)kxi * 32 + ky0;
        float4 r0 = *(const float4*)pr, r1 = *(const float4*)(pr + 4);
        float4 i0 = *(const float4*)pi, i1 = *(const float4*)(pi + 4);
        float fr[8] = {r0.x, r0.y, r0.z, r0.w, r1.x, r1.y, r1.z, r1.w};
        float fi[8] = {i0.x, i0.y, i0.z, i0.w, i1.x, i1.y, i1.z, i1.w};
#pragma unroll
        for (int q = 0; q < 8; ++q) {
            int ky = ky0 + q;
            float sc = ((ky == 0) ? 1.f : 2.f) * (1.f / 65536.f);
            float vr = fr[q] * sc, vi = fi[q] * sc;
            float vrh = bf16tof(bf16r(vr)), vih = bf16tof(bf16r(vi));
            float vrl = vr - vrh, vil = vi - vih;
            *(unsigned*)&Gh[(2 * ky) * IF_PITCH + 2 * kxi]     = pack2(vr, -vi);
            *(unsigned*)&Gh[(2 * ky + 1) * IF_PITCH + 2 * kxi] = pack2(vi, vr);
            *(unsigned*)&Gl[(2 * ky) * IF_PITCH + 2 * kxi]     = pack2(vrl, -vil);
            *(unsigned*)&Gl[(2 * ky + 1) * IF_PITCH + 2 * kxi] = pack2(vil, vrl);
        }
    }

    int hl_ = t & 63;                  // F-builder row
    int g = t >> 6;                    // kxi group
    int kxi0 = g * 16;
    int kx0 = (g < 2) ? kxi0 : kxi0 + 192;

    for (int hc = 0; hc < 4; ++hc) {
        int h = hc * 64 + hl_;
        {
            float c1, s1;
            __sincosf(PI2_256 * (float)h, &s1, &c1);            // step e^{+i 2pi h/256}
            float c, s;
            __sincosf(PI2_256 * (float)((kx0 * h) & 255), &s, &c);
#pragma unroll
            for (int j = 0; j < 16; ++j) {
                int kk = 2 * (kxi0 + j);
                float ch = bf16tof(bf16r(c)), sh = bf16tof(bf16r(s));
                *(unsigned*)&Fh[hl_ * IF_PITCH + kk] = pack2(c, s);
                *(unsigned*)&Fl[hl_ * IF_PITCH + kk] = pack2(c - ch, s - sh);
                float nc = c * c1 - s * s1;
                s = s * c1 + c * s1;
                c = nc;
            }
        }
        __syncthreads();
        float4v zero = {0.f, 0.f, 0.f, 0.f};
        float4v acc[4];
        acc[0] = zero; acc[1] = zero; acc[2] = zero; acc[3] = zero;
#pragma unroll
        for (int ks = 0; ks < 4; ++ks) {
            int ko = ks * 32 + quad * 8;
            short8 bh = *(const short8*)&Gh[(wid * 16 + col) * IF_PITCH + ko];
            short8 bl = *(const short8*)&Gl[(wid * 16 + col) * IF_PITCH + ko];
#pragma unroll
            for (int mt = 0; mt < 4; ++mt) {
                int ro = (mt * 16 + col) * IF_PITCH + ko;
                short8 ah = *(const short8*)&Fh[ro];
                short8 al = *(const short8*)&Fl[ro];
                acc[mt] = __builtin_amdgcn_mfma_f32_16x16x32_bf16(ah, bh, acc[mt], 0, 0, 0);
                acc[mt] = __builtin_amdgcn_mfma_f32_16x16x32_bf16(ah, bl, acc[mt], 0, 0, 0);
                acc[mt] = __builtin_amdgcn_mfma_f32_16x16x32_bf16(al, bh, acc[mt], 0, 0, 0);
            }
        }
        // ---- store: T[bo][hc*64 + mt*16+quad*4+reg][wid*16+col] ----
        float* dst = T + (size_t)bo * 16384 + (size_t)hc * 4096;
#pragma unroll
        for (int mt = 0; mt < 4; ++mt) {
#pragma unroll
            for (int reg = 0; reg < 4; ++reg) {
                int hh = mt * 16 + quad * 4 + reg;
                dst[hh * 64 + wid * 16 + col] = acc[mt][reg];
            }
        }
        __syncthreads();   // F reads done before next chunk's rebuild
    }
}

// ---------------------------------------------------------------------------
// K5 (MFMA): per (b,h,w-half): D[32 o x 128 w] = A[32 x 160] * B[160 x 128]
//   A = [ cw (96) | Tr (32) | Ti (32) ]   (bf16, pre-packed in lane order)
//   B = [ x; dh; dw (96) | cos (32) | -sin (32) ]  rows, built in LDS bf16.
//   FP32 accumulation via v_mfma_f32_16x16x32_bf16.
// ---------------------------------------------------------------------------
#define BT_PITCH 164   // bf16 elements per Bt row (41 dwords: odd mod 32 -> 2-way max)

__global__ __launch_bounds__(256) void k_final(const float* __restrict__ x,
                                               const float* __restrict__ cw,
                                               const float* __restrict__ cb,
                                               const float* __restrict__ T,
                                               float* __restrict__ out) {
    __shared__ unsigned short Bt[128 * BT_PITCH];        // [n][k] 41,984 B
    __shared__ __align__(16) unsigned short Afr[5 * 2 * 64 * 8];  // [ks][mt][lane][8] 10,240 B

    int t = threadIdx.x;
    int b = blockIdx.x >> 9;
    int h = (blockIdx.x >> 1) & 255;
    int w0 = (blockIdx.x & 1) << 7;

    // ---- stage B: feats rows (k=0..95) ----
    {
        int nn = t & 127, half = t >> 7;       // half picks i-range 0..15 / 16..31
        int w = w0 + nn;
        int hs = (h < 255) ? h + 1 : h;
        int we = (w < 255) ? 1 : 0;
#pragma unroll
        for (int ip = 0; ip < 8; ++ip) {
            int i0 = half * 16 + ip * 2;
            const float* x0 = x + ((size_t)(b * 32 + i0)) * 65536;
            const float* x1 = x0 + 65536;
            float c0 = x0[h * 256 + w];
            float s0 = x0[hs * 256 + w];
            float e0 = x0[h * 256 + w + we];
            float c1 = x1[h * 256 + w];
            float s1 = x1[hs * 256 + w];
            float e1 = x1[h * 256 + w + we];
            *(unsigned*)&Bt[nn * BT_PITCH + i0]      = pack2(c0, c1);
            *(unsigned*)&Bt[nn * BT_PITCH + 32 + i0] = pack2(s0 - c0, s1 - c1);
            *(unsigned*)&Bt[nn * BT_PITCH + 64 + i0] = pack2(e0 - c0, e1 - c1);
        }
    }
    // ---- stage B: twiddle rows (k=96..159): cos(2pi kk w/256), -sin(...) ----
    {
        int nn = t & 127, half = t >> 7;
        int w = w0 + nn;
        float c1, s1;
        __sincosf(PI2_256 * (float)w, &s1, &c1);
        int kk0 = half * 16;
        float c, s;
        __sincosf(PI2_256 * (float)((w * kk0) & 255), &s, &c);
#pragma unroll
        for (int kp = 0; kp < 8; ++kp) {
            int kk = kk0 + kp * 2;
            float ca = c, sa = s;
            float nc = c * c1 - s * s1; s = s * c1 + c * s1; c = nc;   // kk+1
            float cbv = c, sbv = s;
            nc = c * c1 - s * s1; s = s * c1 + c * s1; c = nc;         // kk+2
            *(unsigned*)&Bt[nn * BT_PITCH + 96 + kk]  = pack2(ca, cbv);
            *(unsigned*)&Bt[nn * BT_PITCH + 128 + kk] = pack2(-sa, -sbv);
        }
    }
    // ---- stage A fragments: lane-order pack of [cw | Tr | Ti] ----
    for (int slot = t; slot < 640; slot += 256) {
        int ks = slot >> 7;            // 0..4
        int mt = (slot >> 6) & 1;
        int lane = slot & 63;
        int m = (lane & 15) + mt * 16; // output channel o
        int kb = ks * 32 + (lane >> 4) * 8;
        float v[8];
        if (ks < 3) {
#pragma unroll
            for (int j = 0; j < 8; ++j) v[j] = cw[m * 96 + kb + j];
        } else {
            const float* tp = T + ((size_t)(b * 32 + m)) * 16384 + (size_t)h * 64;
            int kkb = kb - (ks == 3 ? 96 : 128);
            int im = (ks == 3) ? 0 : 1;
#pragma unroll
            for (int j = 0; j < 8; ++j) v[j] = tp[2 * (kkb + j) + im];
        }
        uint4 pk;
        pk.x = pack2(v[0], v[1]); pk.y = pack2(v[2], v[3]);
        pk.z = pack2(v[4], v[5]); pk.w = pack2(v[6], v[7]);
        *(uint4*)&Afr[((ks * 2 + mt) * 64 + lane) * 8] = pk;
    }
    __syncthreads();

    // ---- MFMA K-loop ----
    int lane = t & 63, wid = t >> 6;
    int quad = lane >> 4, col = lane & 15;
    float4v zero = {0.f, 0.f, 0.f, 0.f};
    float4v acc[2][2];
    acc[0][0] = zero; acc[0][1] = zero; acc[1][0] = zero; acc[1][1] = zero;

#pragma unroll
    for (int ks = 0; ks < 5; ++ks) {
        short8 a0 = *(const short8*)&Afr[((ks * 2 + 0) * 64 + lane) * 8];
        short8 a1 = *(const short8*)&Afr[((ks * 2 + 1) * 64 + lane) * 8];
        int kb = ks * 32 + quad * 8;
        union { unsigned long long q[2]; short8 v; } ub0, ub1;
        const unsigned short* r0 = &Bt[(wid * 32 + col) * BT_PITCH + kb];
        const unsigned short* r1 = &Bt[(wid * 32 + 16 + col) * BT_PITCH + kb];
        ub0.q[0] = *(const unsigned long long*)(r0);
        ub0.q[1] = *(const unsigned long long*)(r0 + 4);
        ub1.q[0] = *(const unsigned long long*)(r1);
        ub1.q[1] = *(const unsigned long long*)(r1 + 4);
        acc[0][0] = __builtin_amdgcn_mfma_f32_16x16x32_bf16(a0, ub0.v, acc[0][0], 0, 0, 0);
        acc[1][0] = __builtin_amdgcn_mfma_f32_16x16x32_bf16(a1, ub0.v, acc[1][0], 0, 0, 0);
        acc[0][1] = __builtin_amdgcn_mfma_f32_16x16x32_bf16(a0, ub1.v, acc[0][1], 0, 0, 0);
        acc[1][1] = __builtin_amdgcn_mfma_f32_16x16x32_bf16(a1, ub1.v, acc[1][1], 0, 0, 0);
    }

    // ---- epilogue: C/D layout col=lane&15, row=quad*4+reg; add bias ----
#pragma unroll
    for (int mt = 0; mt < 2; ++mt) {
#pragma unroll
        for (int nt = 0; nt < 2; ++nt) {
#pragma unroll
            for (int reg = 0; reg < 4; ++reg) {
                int o = mt * 16 + quad * 4 + reg;
                int w = w0 + wid * 32 + nt * 16 + col;
                out[(((size_t)(b * 32 + o)) * 256 + h) * 256 + w] = acc[mt][nt][reg] + cb[o];
            }
        }
    }
}

// ---------------------------------------------------------------------------
extern "C" void kernel_launch(void* const* d_in, const int* in_sizes, int n_in,
                              void* d_out, int out_size, void* d_ws, size_t ws_size,
                              hipStream_t stream) {
    const float* x = (const float*)d_in[0];
    const float* conv_w = (const float*)d_in[1];
    const float* conv_b = (const float*)d_in[2];
    const float* w1r = (const float*)d_in[3];
    const float* w1i = (const float*)d_in[4];
    const float* w2r = (const float*)d_in[5];
    const float* w2i = (const float*)d_in[6];
    float* out = (float*)d_out;

    float* ws = (float*)d_ws;
    float* Ar = ws;                    // 4,194,304 floats: A real  [bc][h][ky]
    float* Ai = ws + 4194304;          // 4,194,304 floats: A imag
    float* Tbuf = ws;                  // 8,388,608 floats: T [bo][h][2ky] (reuses A region)
    float* xfr = ws + 8388608;         // 1,048,576 floats: xf/of real [bc][kxi][ky]
    float* xfi = ws + 9437184;         // 1,048,576 floats: xf/of imag
    const float* Ews = ws + 8388608;   // 73,728 B twiddle table (xfr region; k_dfth
                                       // overwrites it AFTER k_dftw has consumed it)
    // total workspace: 10,485,760 floats = 40 MiB

    k_twiddle<<<16, 256, 0, stream>>>(ws);
    k_dftw<<<1024, 256, 0, stream>>>(x, Ews, Ar, Ai);
    k_dfth<<<512, 256, 0, stream>>>(Ar, Ai, xfr, xfi);
    k_mix<<<1024, 256, 0, stream>>>(xfr, xfi, w1r, w1i, w2r, w2i);
    k_idfth<<<512, 256, 0, stream>>>(xfr, xfi, Tbuf);
    k_final<<<8192, 256, 0, stream>>>(x, conv_w, conv_b, Tbuf, out);
}

// Round 4
// 427.943 us; speedup vs baseline: 1.3633x; 1.0091x over previous
//
#include <hip/hip_runtime.h>

// Combi layer: diff-stencil 1x1 conv + truncated spectral conv.
// B=16, C=32 (in=out), H=W=256, modes M1=M2=32.
// R1: k_dftw as bf16 MFMA GEMM with hi/lo split precision.
// R2/R3: k_dfth and k_idfth converted the same way.
// R4: k_final restaged - precomputed twiddle/cw tables (k_tables), T stored as
//     bf16 fragment-ready layout by k_idfth, B staged in MFMA-frag order
//     (LDS 52->40 KB, 4 blocks/CU, lane-contiguous b128 LDS ops).

#define PI2_256 0.02454369260617026f   // 2*pi/256

__device__ __forceinline__ unsigned short bf16r(float f) {
    unsigned u = __float_as_uint(f);
    u += 0x7fffu + ((u >> 16) & 1u);   // round-to-nearest-even
    return (unsigned short)(u >> 16);
}
__device__ __forceinline__ float bf16tof(unsigned short h) {
    return __uint_as_float((unsigned)h << 16);
}
__device__ __forceinline__ unsigned pack2(float a, float b) {
    return (unsigned)bf16r(a) | ((unsigned)bf16r(b) << 16);
}

typedef __attribute__((ext_vector_type(8))) short short8;
typedef __attribute__((ext_vector_type(4))) float float4v;

// ---------------------------------------------------------------------------
// K0: build DFT-w twiddle table E (bf16 hi + lo) in workspace (for k_dftw).
// Lives at ws + 8388608 floats (xfr region; overwritten later by k_dfth - OK).
// ---------------------------------------------------------------------------
__global__ __launch_bounds__(256) void k_twiddle(float* __restrict__ ws) {
    unsigned short* E = (unsigned short*)(ws + 8388608);
    int idx0 = blockIdx.x * 256 + threadIdx.x;
    for (int idx = idx0; idx < 4 * 64 * 72; idx += 16 * 256) {
        int c = idx / 4608;
        int rem = idx - c * 4608;
        int col = rem / 72;
        int wp = rem - col * 72;
        unsigned short hi = 0, lo = 0;
        if (wp < 64) {
            int w = c * 64 + wp;
            int ky = col & 31;
            int prod = (ky * w) & 255;
            float s, cc;
            __sincosf(PI2_256 * (float)prod, &s, &cc);
            float val = (col < 32) ? cc : -s;
            hi = bf16r(val);
            lo = bf16r(val - bf16tof(hi));
        }
        E[c * 9216 + col * 72 + wp] = hi;
        E[c * 9216 + 4608 + col * 72 + wp] = lo;
    }
}

// ---------------------------------------------------------------------------
// K0b: tables for k_final, written into the Ai region (dead after k_dfth).
//   TW  at ws+6291456 (floats): [w][kk] bf16, kk<32: cos(2pi kk w/256),
//                               kk>=32: -sin(2pi (kk-32) w/256).  32 KB.
//   CWf at ws+6301696 (floats): pre-packed cw A-frags [ks][mt][lane][8]. 6 KB.
// ---------------------------------------------------------------------------
__global__ __launch_bounds__(256) void k_tables(const float* __restrict__ cw,
                                                float* __restrict__ ws) {
    unsigned short* TWt = (unsigned short*)(ws + 6291456);
    unsigned short* CWf = (unsigned short*)(ws + 6301696);
    int id = blockIdx.x * 256 + threadIdx.x;   // grid 64*256 = 16384 = TW size
    int w = id >> 6, kk = id & 63;
    float s, c;
    __sincosf(PI2_256 * (float)(((kk & 31) * w) & 255), &s, &c);
    TWt[id] = bf16r(kk < 32 ? c : -s);
    if (id < 3072) {
        int j = id & 7, slot = id >> 3;
        int ks = slot >> 7, mt = (slot >> 6) & 1, lane = slot & 63;
        int m = (lane & 15) + mt * 16;
        int kb = ks * 32 + ((lane >> 4) & 3) * 8;
        CWf[id] = bf16r(cw[m * 96 + kb + j]);
    }
}

// ---------------------------------------------------------------------------
// K1 (MFMA): A[bc][h][ky] = sum_w x[bc][h][w] * e^{-2pi i ky w/256}, ky=0..31
// ---------------------------------------------------------------------------
__global__ __launch_bounds__(256) void k_dftw(const float* __restrict__ x,
                                              const float* __restrict__ Ews,
                                              float* __restrict__ Ar,
                                              float* __restrict__ Ai) {
    __shared__ __align__(16) unsigned char smem[55296];
    unsigned short* Xhi = (unsigned short*)smem;              // [128][72] bf16
    unsigned short* Xlo = (unsigned short*)(smem + 18432);    // [128][72]
    unsigned short* Ehi = (unsigned short*)(smem + 36864);    // [64][72], Elo at +4608
    float* obuf = (float*)smem;                               // [128][68] epilogue reuse

    int t = threadIdx.x;
    int bc = blockIdx.x >> 1;
    int h0 = (blockIdx.x & 1) << 7;
    int lane = t & 63, wid = t >> 6;
    int quad = lane >> 4, col = lane & 15;

    const uint4* Ews4 = (const uint4*)Ews;

    float4v zero = {0.f, 0.f, 0.f, 0.f};
    float4v acc[4][2];
#pragma unroll
    for (int m = 0; m < 4; ++m) {
        acc[m][0] = zero;
        acc[m][1] = zero;
    }

    for (int c = 0; c < 4; ++c) {
        // ---- stage X chunk [128 h][64 w] -> bf16 hi/lo, pitch 72 ----
        const float* xrow = x + ((size_t)bc * 256 + h0) * 256 + c * 64;
#pragma unroll
        for (int it = 0; it < 8; ++it) {
            int l = it * 256 + t;
            int r = l >> 4, f4 = l & 15;
            float4 v = *(const float4*)(xrow + (size_t)r * 256 + f4 * 4);
            unsigned short hx = bf16r(v.x), hy = bf16r(v.y);
            unsigned short hz = bf16r(v.z), hw = bf16r(v.w);
            unsigned hi0 = (unsigned)hx | ((unsigned)hy << 16);
            unsigned hi1 = (unsigned)hz | ((unsigned)hw << 16);
            unsigned lo0 = (unsigned)bf16r(v.x - bf16tof(hx)) |
                           ((unsigned)bf16r(v.y - bf16tof(hy)) << 16);
            unsigned lo1 = (unsigned)bf16r(v.z - bf16tof(hz)) |
                           ((unsigned)bf16r(v.w - bf16tof(hw)) << 16);
            int o = r * 72 + f4 * 4;
            *(uint2*)&Xhi[o] = make_uint2(hi0, hi1);
            *(uint2*)&Xlo[o] = make_uint2(lo0, lo1);
        }
        // ---- stage E chunk (hi+lo image, 1152 x 16B) ----
        for (int g = t; g < 1152; g += 256)
            ((uint4*)(smem + 36864))[g] = Ews4[c * 1152 + g];
        __syncthreads();

        // ---- MFMA: 2 K-steps of 32 per chunk ----
#pragma unroll
        for (int ks = 0; ks < 2; ++ks) {
            int ko = quad * 8 + ks * 32;
            short8 ah[4], al[4], bh[2], bl[2];
#pragma unroll
            for (int m = 0; m < 4; ++m) {
                int ro = (m * 16 + col) * 72 + ko;
                ah[m] = *(const short8*)&Ehi[ro];
                al[m] = *(const short8*)&Ehi[4608 + ro];
            }
#pragma unroll
            for (int n = 0; n < 2; ++n) {
                int hr = ((wid * 2 + n) * 16 + col) * 72 + ko;
                bh[n] = *(const short8*)&Xhi[hr];
                bl[n] = *(const short8*)&Xlo[hr];
            }
#pragma unroll
            for (int m = 0; m < 4; ++m) {
#pragma unroll
                for (int n = 0; n < 2; ++n) {
                    acc[m][n] = __builtin_amdgcn_mfma_f32_16x16x32_bf16(ah[m], bh[n], acc[m][n], 0, 0, 0);
                    acc[m][n] = __builtin_amdgcn_mfma_f32_16x16x32_bf16(ah[m], bl[n], acc[m][n], 0, 0, 0);
                    acc[m][n] = __builtin_amdgcn_mfma_f32_16x16x32_bf16(al[m], bh[n], acc[m][n], 0, 0, 0);
                }
            }
        }
        __syncthreads();
    }

    // ---- epilogue: D[m][n] -> obuf[h_local][m] (transpose), then coalesced store ----
#pragma unroll
    for (int m = 0; m < 4; ++m) {
#pragma unroll
        for (int n = 0; n < 2; ++n) {
            int hl = (wid * 2 + n) * 16 + col;
            *(float4v*)&obuf[hl * 68 + m * 16 + quad * 4] = acc[m][n];
        }
    }
    __syncthreads();
#pragma unroll
    for (int it = 0; it < 8; ++it) {
        int l = it * 256 + t;
        int hh = l >> 4, f = l & 15;
        float4 v = *(float4*)&obuf[hh * 68 + f * 4];
        size_t g = (size_t)bc * 8192 + (size_t)(h0 + hh) * 32;
        if (f < 8) *(float4*)(Ar + g + f * 4) = v;
        else       *(float4*)(Ai + g + (f - 8) * 4) = v;
    }
}

// ---------------------------------------------------------------------------
// K2 (MFMA): xf[bc][kxi][ky] = sum_h A[bc][h][ky] * e^{-2pi i kx h/256}
// ---------------------------------------------------------------------------
#define DF_PITCH 72   // shorts/row = 36 dwords == 4 mod 32 -> uniform bank spread

__global__ __launch_bounds__(256) void k_dfth(const float* __restrict__ Ar,
                                              const float* __restrict__ Ai,
                                              float* __restrict__ xfr,
                                              float* __restrict__ xfi) {
    __shared__ __align__(16) unsigned short F2h[128 * DF_PITCH];
    __shared__ __align__(16) unsigned short F2l[128 * DF_PITCH];
    __shared__ __align__(16) unsigned short B2h[32 * DF_PITCH];
    __shared__ __align__(16) unsigned short B2l[32 * DF_PITCH];

    int t = threadIdx.x;
    int bc = blockIdx.x;
    int lane = t & 63, wid = t >> 6;
    int quad = lane >> 4, col = lane & 15;

    int m = t & 127;
    int kxi = m >> 1;
    int kx = (kxi < 32) ? kxi : kxi + 192;
    int neg = m & 1;
    int khalf = t >> 7;
    float c1, s1;
    __sincosf(PI2_256 * (float)kx, &s1, &c1);   // per-h step e^{+i 2pi kx/256}

    float4v zero = {0.f, 0.f, 0.f, 0.f};
    float4v acc[2][2];
    acc[0][0] = zero; acc[0][1] = zero; acc[1][0] = zero; acc[1][1] = zero;

    for (int hc = 0; hc < 8; ++hc) {
        // ---- F2 tile ----
        {
            int h0 = hc * 32 + khalf * 16;
            float c, s;
            __sincosf(PI2_256 * (float)((kx * h0) & 255), &s, &c);
#pragma unroll
            for (int j = 0; j < 16; ++j) {
                int kk = 2 * (khalf * 16 + j);
                float ch = bf16tof(bf16r(c)), sh = bf16tof(bf16r(s));
                float cl = c - ch, sl = s - sh;
                unsigned hiw, low;
                if (neg == 0) { hiw = pack2(c, s);  low = pack2(cl, sl); }
                else          { hiw = pack2(-s, c); low = pack2(-sl, cl); }
                *(unsigned*)&F2h[m * DF_PITCH + kk] = hiw;
                *(unsigned*)&F2l[m * DF_PITCH + kk] = low;
                float nc = c * c1 - s * s1;
                s = s * c1 + c * s1;
                c = nc;
            }
        }
        // ---- B2 tile ----
        {
            int hl = t >> 3;               // 0..31
            int ky0 = (t & 7) * 4;
            const float* pr = Ar + (size_t)bc * 8192 + (size_t)(hc * 32 + hl) * 32 + ky0;
            const float* pi = Ai + (size_t)bc * 8192 + (size_t)(hc * 32 + hl) * 32 + ky0;
            float4 vr = *(const float4*)pr;
            float4 vi = *(const float4*)pi;
            float fr[4] = {vr.x, vr.y, vr.z, vr.w};
            float fi[4] = {vi.x, vi.y, vi.z, vi.w};
#pragma unroll
            for (int q = 0; q < 4; ++q) {
                float ar = fr[q], ai = fi[q];
                float arh = bf16tof(bf16r(ar)), aih = bf16tof(bf16r(ai));
                *(unsigned*)&B2h[(ky0 + q) * DF_PITCH + 2 * hl] = pack2(ar, ai);
                *(unsigned*)&B2l[(ky0 + q) * DF_PITCH + 2 * hl] = pack2(ar - arh, ai - aih);
            }
        }
        __syncthreads();
        // ---- MFMA: 2 K-steps of 32 ----
#pragma unroll
        for (int ks = 0; ks < 2; ++ks) {
            int ko = ks * 32 + quad * 8;
            short8 ah[2], al[2], bh[2], bl[2];
#pragma unroll
            for (int mi = 0; mi < 2; ++mi) {
                int ro = ((wid * 2 + mi) * 16 + col) * DF_PITCH + ko;
                ah[mi] = *(const short8*)&F2h[ro];
                al[mi] = *(const short8*)&F2l[ro];
            }
#pragma unroll
            for (int ni = 0; ni < 2; ++ni) {
                int ro = (ni * 16 + col) * DF_PITCH + ko;
                bh[ni] = *(const short8*)&B2h[ro];
                bl[ni] = *(const short8*)&B2l[ro];
            }
#pragma unroll
            for (int mi = 0; mi < 2; ++mi) {
#pragma unroll
                for (int ni = 0; ni < 2; ++ni) {
                    acc[mi][ni] = __builtin_amdgcn_mfma_f32_16x16x32_bf16(ah[mi], bh[ni], acc[mi][ni], 0, 0, 0);
                    acc[mi][ni] = __builtin_amdgcn_mfma_f32_16x16x32_bf16(ah[mi], bl[ni], acc[mi][ni], 0, 0, 0);
                    acc[mi][ni] = __builtin_amdgcn_mfma_f32_16x16x32_bf16(al[mi], bh[ni], acc[mi][ni], 0, 0, 0);
                }
            }
        }
        __syncthreads();
    }
    // ---- epilogue ----
#pragma unroll
    for (int mi = 0; mi < 2; ++mi) {
#pragma unroll
        for (int ni = 0; ni < 2; ++ni) {
#pragma unroll
            for (int reg = 0; reg < 4; ++reg) {
                int mm = (wid * 2 + mi) * 16 + quad * 4 + reg;
                size_t g = (size_t)bc * 2048 + (size_t)(mm >> 1) * 32 + ni * 16 + col;
                if (mm & 1) xfi[g] = acc[mi][ni][reg];
                else        xfr[g] = acc[mi][ni][reg];
            }
        }
    }
}

// ---------------------------------------------------------------------------
// K3: in-place per-mode complex channel mix (batch-split across blocks)
// ---------------------------------------------------------------------------
__global__ __launch_bounds__(256) void k_mix(float* __restrict__ xfr,
                                             float* __restrict__ xfi,
                                             const float* __restrict__ w1r,
                                             const float* __restrict__ w1i,
                                             const float* __restrict__ w2r,
                                             const float* __restrict__ w2i) {
    __shared__ float wr[32 * 32 * 8];   // [i][o][q]
    __shared__ float wi[32 * 32 * 8];
    __shared__ float xsr[32 * 8];       // [i][q]
    __shared__ float xsi[32 * 8];
    int t = threadIdx.x;
    int kxi = (blockIdx.x >> 2) & 63;
    int ky0 = (blockIdx.x & 3) * 8;
    int b0 = (blockIdx.x >> 8) * 4;     // 4 batches per block
    const float* Wr = (kxi < 32) ? w1r : w2r;
    const float* Wi = (kxi < 32) ? w1i : w2i;
    int m1 = kxi & 31;
#pragma unroll
    for (int it = 0; it < 32; ++it) {
        int l = it * 256 + t;                 // l = i*256 + o*8 + q
        int i = l >> 8, o = (l >> 3) & 31, q = l & 7;
        size_t g = (size_t)i * 32768 + (size_t)o * 1024 + m1 * 32 + ky0 + q;
        wr[l] = Wr[g];
        wi[l] = Wi[g];
    }
    __syncthreads();

    int o = t >> 3, q = t & 7;
    for (int b = b0; b < b0 + 4; ++b) {
        __syncthreads();
        {
            int i = t >> 3, qq = t & 7;
            size_t g = ((size_t)(b * 32 + i)) * 2048 + (size_t)kxi * 32 + ky0 + qq;
            xsr[t] = xfr[g];
            xsi[t] = xfi[g];
        }
        __syncthreads();
        float accr = 0.f, acci = 0.f;
#pragma unroll
        for (int i = 0; i < 32; ++i) {
            float xr = xsr[i * 8 + q], xim = xsi[i * 8 + q];
            float wrv = wr[i * 256 + o * 8 + q], wiv = wi[i * 256 + o * 8 + q];
            accr += xr * wrv - xim * wiv;
            acci += xr * wiv + xim * wrv;
        }
        size_t g = ((size_t)(b * 32 + o)) * 2048 + (size_t)kxi * 32 + ky0 + q;
        xfr[g] = accr;   // safe: only this block touches this (b,kxi,ky) slice
        xfi[g] = acci;
    }
}

// ---------------------------------------------------------------------------
// K4 (MFMA): T2[bo][h][n] (bf16), n = im*32+ky:
//   T2 = scale * {Re,Im} sum_kxi of[bo,kxi,ky]*e^{+2pi i kx h/256}
//   GEMM per bo: D[256 h][64 n], K = 128 (k = 2kxi+{cos,sin}).
// ---------------------------------------------------------------------------
#define IF_PITCH 136  // shorts/row = 68 dwords == 4 mod 32, rows 16B-aligned

__global__ __launch_bounds__(256) void k_idfth(const float* __restrict__ ofr,
                                               const float* __restrict__ ofi,
                                               unsigned short* __restrict__ T2) {
    __shared__ __align__(16) unsigned short Fh[64 * IF_PITCH];
    __shared__ __align__(16) unsigned short Fl[64 * IF_PITCH];
    __shared__ __align__(16) unsigned short Gh[64 * IF_PITCH];
    __shared__ __align__(16) unsigned short Gl[64 * IF_PITCH];

    int t = threadIdx.x;
    int bo = blockIdx.x;
    int lane = t & 63, wid = t >> 6;
    int quad = lane >> 4, col = lane & 15;

    // ---- build G: row n = ky holds (vr,-vi) pairs; row 32+ky holds (vi,vr) ----
    {
        int kxi = t >> 2;               // 0..63
        int ky0 = (t & 3) * 8;
        const float* pr = ofr + (size_t)bo * 2048 + (size_t)kxi * 32 + ky0;
        const float* pi = ofi + (size_t)bo * 2048 + (size_t)kxi * 32 + ky0;
        float4 r0 = *(const float4*)pr, r1 = *(const float4*)(pr + 4);
        float4 i0 = *(const float4*)pi, i1 = *(const float4*)(pi + 4);
        float fr[8] = {r0.x, r0.y, r0.z, r0.w, r1.x, r1.y, r1.z, r1.w};
        float fi[8] = {i0.x, i0.y, i0.z, i0.w, i1.x, i1.y, i1.z, i1.w};
#pragma unroll
        for (int q = 0; q < 8; ++q) {
            int ky = ky0 + q;
            float sc = ((ky == 0) ? 1.f : 2.f) * (1.f / 65536.f);
            float vr = fr[q] * sc, vi = fi[q] * sc;
            float vrh = bf16tof(bf16r(vr)), vih = bf16tof(bf16r(vi));
            float vrl = vr - vrh, vil = vi - vih;
            *(unsigned*)&Gh[ky * IF_PITCH + 2 * kxi]        = pack2(vr, -vi);
            *(unsigned*)&Gh[(32 + ky) * IF_PITCH + 2 * kxi] = pack2(vi, vr);
            *(unsigned*)&Gl[ky * IF_PITCH + 2 * kxi]        = pack2(vrl, -vil);
            *(unsigned*)&Gl[(32 + ky) * IF_PITCH + 2 * kxi] = pack2(vil, vrl);
        }
    }

    int hl_ = t & 63;                  // F-builder row
    int g = t >> 6;                    // kxi group
    int kxi0 = g * 16;
    int kx0 = (g < 2) ? kxi0 : kxi0 + 192;

    for (int hc = 0; hc < 4; ++hc) {
        int h = hc * 64 + hl_;
        {
            float c1, s1;
            __sincosf(PI2_256 * (float)h, &s1, &c1);            // step e^{+i 2pi h/256}
            float c, s;
            __sincosf(PI2_256 * (float)((kx0 * h) & 255), &s, &c);
#pragma unroll
            for (int j = 0; j < 16; ++j) {
                int kk = 2 * (kxi0 + j);
                float ch = bf16tof(bf16r(c)), sh = bf16tof(bf16r(s));
                *(unsigned*)&Fh[hl_ * IF_PITCH + kk] = pack2(c, s);
                *(unsigned*)&Fl[hl_ * IF_PITCH + kk] = pack2(c - ch, s - sh);
                float nc = c * c1 - s * s1;
                s = s * c1 + c * s1;
                c = nc;
            }
        }
        __syncthreads();
        float4v zero = {0.f, 0.f, 0.f, 0.f};
        float4v acc[4];
        acc[0] = zero; acc[1] = zero; acc[2] = zero; acc[3] = zero;
#pragma unroll
        for (int ks = 0; ks < 4; ++ks) {
            int ko = ks * 32 + quad * 8;
            short8 bh = *(const short8*)&Gh[(wid * 16 + col) * IF_PITCH + ko];
            short8 bl = *(const short8*)&Gl[(wid * 16 + col) * IF_PITCH + ko];
#pragma unroll
            for (int mt = 0; mt < 4; ++mt) {
                int ro = (mt * 16 + col) * IF_PITCH + ko;
                short8 ah = *(const short8*)&Fh[ro];
                short8 al = *(const short8*)&Fl[ro];
                acc[mt] = __builtin_amdgcn_mfma_f32_16x16x32_bf16(ah, bh, acc[mt], 0, 0, 0);
                acc[mt] = __builtin_amdgcn_mfma_f32_16x16x32_bf16(ah, bl, acc[mt], 0, 0, 0);
                acc[mt] = __builtin_amdgcn_mfma_f32_16x16x32_bf16(al, bh, acc[mt], 0, 0, 0);
            }
        }
        // ---- store bf16: T2[bo][hc*64 + mt*16+quad*4+reg][wid*16+col] ----
        unsigned short* dst = T2 + (size_t)bo * 16384 + (size_t)hc * 64 * 64;
        int n = wid * 16 + col;
#pragma unroll
        for (int mt = 0; mt < 4; ++mt) {
#pragma unroll
            for (int reg = 0; reg < 4; ++reg) {
                int hh = mt * 16 + quad * 4 + reg;
                dst[hh * 64 + n] = bf16r(acc[mt][reg]);
            }
        }
        __syncthreads();   // F reads done before next chunk's rebuild
    }
}

// ---------------------------------------------------------------------------
// K5 (MFMA): per (b,h,w-half): D[32 o x 128 w] = A[32 x 160] * B[160 x 128]
//   A = [ cw (96) | Tr (32) | Ti (32) ]  loaded directly into registers
//       (cw from CWf table; Tr/Ti from T2 bf16 frag-ready layout).
//   B = [ x; dh; dw (96) | cos (32) | -sin (32) ] staged in MFMA-frag order
//       Bf[ks][wt][lane][8] -> lane-contiguous b128, LDS = 40,960 B.
// ---------------------------------------------------------------------------
__global__ __launch_bounds__(256, 4) void k_final(const float* __restrict__ x,
                                                  const unsigned short* __restrict__ cwf,
                                                  const unsigned short* __restrict__ TWt,
                                                  const float* __restrict__ cb,
                                                  const unsigned short* __restrict__ T2,
                                                  float* __restrict__ out) {
    __shared__ __align__(16) unsigned short Bf[5 * 8 * 64 * 8];   // 40,960 B

    int t = threadIdx.x;
    int b = blockIdx.x >> 9;
    int h = (blockIdx.x >> 1) & 255;
    int w0 = (blockIdx.x & 1) << 7;
    int lane = t & 63, wid = t >> 6;
    int quad = lane >> 4, col = lane & 15;

    // ---- A fragments: direct per-thread loads (issued early) ----
    short8 a[5][2];
#pragma unroll
    for (int ks = 0; ks < 3; ++ks)
#pragma unroll
        for (int mt = 0; mt < 2; ++mt)
            a[ks][mt] = *(const short8*)&cwf[((ks * 2 + mt) * 64 + lane) * 8];
#pragma unroll
    for (int ks = 3; ks < 5; ++ks)
#pragma unroll
        for (int mt = 0; mt < 2; ++mt) {
            int m = (lane & 15) + mt * 16;
            a[ks][mt] = *(const short8*)&T2[((size_t)(b * 32 + m) * 256 + h) * 64
                                            + (ks - 3) * 32 + quad * 8];
        }

    // ---- stage B feats (k = 0..95), frag order ----
    int nn = t & 127, half = t >> 7;
    int w = w0 + nn;
    int wt = nn >> 4, colw = nn & 15;
    int hs = (h < 255) ? h + 1 : h;
    int we = (w < 255) ? 1 : 0;
#pragma unroll
    for (int ip = 0; ip < 2; ++ip) {
        int i0 = half * 16 + ip * 8;
        float c[8], sv[8], ev[8];
#pragma unroll
        for (int j = 0; j < 8; ++j) {
            const float* xp = x + ((size_t)(b * 32 + i0 + j)) * 65536;
            c[j]  = xp[h * 256 + w];
            sv[j] = xp[hs * 256 + w];
            ev[j] = xp[h * 256 + w + we];
        }
        uint4 pc, ps, pe;
        pc.x = pack2(c[0], c[1]); pc.y = pack2(c[2], c[3]);
        pc.z = pack2(c[4], c[5]); pc.w = pack2(c[6], c[7]);
        ps.x = pack2(sv[0] - c[0], sv[1] - c[1]); ps.y = pack2(sv[2] - c[2], sv[3] - c[3]);
        ps.z = pack2(sv[4] - c[4], sv[5] - c[5]); ps.w = pack2(sv[6] - c[6], sv[7] - c[7]);
        pe.x = pack2(ev[0] - c[0], ev[1] - c[1]); pe.y = pack2(ev[2] - c[2], ev[3] - c[3]);
        pe.z = pack2(ev[4] - c[4], ev[5] - c[5]); pe.w = pack2(ev[6] - c[6], ev[7] - c[7]);
        int qp = half * 2 + ip;
        *(uint4*)&Bf[((0 * 8 + wt) * 64 + qp * 16 + colw) * 8] = pc;
        *(uint4*)&Bf[((1 * 8 + wt) * 64 + qp * 16 + colw) * 8] = ps;
        *(uint4*)&Bf[((2 * 8 + wt) * 64 + qp * 16 + colw) * 8] = pe;
    }
    // ---- stage B twiddles from table (k = 96..159) ----
    {
        const uint4* tw = (const uint4*)&TWt[w * 64 + half * 32];
#pragma unroll
        for (int q = 0; q < 4; ++q) {
            uint4 v = tw[q];
            *(uint4*)&Bf[(((3 + half) * 8 + wt) * 64 + q * 16 + colw) * 8] = v;
        }
    }
    __syncthreads();

    // ---- MFMA K-loop: lane-contiguous b128 B reads ----
    float4v zero = {0.f, 0.f, 0.f, 0.f};
    float4v acc[2][2];
    acc[0][0] = zero; acc[0][1] = zero; acc[1][0] = zero; acc[1][1] = zero;
#pragma unroll
    for (int ks = 0; ks < 5; ++ks) {
#pragma unroll
        for (int nt = 0; nt < 2; ++nt) {
            short8 ub = *(const short8*)&Bf[((ks * 8 + wid * 2 + nt) * 64 + lane) * 8];
            acc[0][nt] = __builtin_amdgcn_mfma_f32_16x16x32_bf16(a[ks][0], ub, acc[0][nt], 0, 0, 0);
            acc[1][nt] = __builtin_amdgcn_mfma_f32_16x16x32_bf16(a[ks][1], ub, acc[1][nt], 0, 0, 0);
        }
    }

    // ---- epilogue: C/D layout col=lane&15, row=quad*4+reg; add bias ----
#pragma unroll
    for (int mt = 0; mt < 2; ++mt) {
#pragma unroll
        for (int nt = 0; nt < 2; ++nt) {
#pragma unroll
            for (int reg = 0; reg < 4; ++reg) {
                int o = mt * 16 + quad * 4 + reg;
                int ww = w0 + wid * 32 + nt * 16 + col;
                out[(((size_t)(b * 32 + o)) * 256 + h) * 256 + ww] = acc[mt][nt][reg] + cb[o];
            }
        }
    }
}

// ---------------------------------------------------------------------------
extern "C" void kernel_launch(void* const* d_in, const int* in_sizes, int n_in,
                              void* d_out, int out_size, void* d_ws, size_t ws_size,
                              hipStream_t stream) {
    const float* x = (const float*)d_in[0];
    const float* conv_w = (const float*)d_in[1];
    const float* conv_b = (const float*)d_in[2];
    const float* w1r = (const float*)d_in[3];
    const float* w1i = (const float*)d_in[4];
    const float* w2r = (const float*)d_in[5];
    const float* w2i = (const float*)d_in[6];
    float* out = (float*)d_out;

    float* ws = (float*)d_ws;
    float* Ar = ws;                    // 4,194,304 floats: A real  [bc][h][ky]
    float* Ai = ws + 4194304;          // 4,194,304 floats: A imag
    unsigned short* T2 = (unsigned short*)ws;  // 8,388,608 bf16: T2 [bo][h][64] (reuses Ar)
    float* xfr = ws + 8388608;         // 1,048,576 floats: xf/of real [bc][kxi][ky]
    float* xfi = ws + 9437184;         // 1,048,576 floats: xf/of imag
    const float* Ews = ws + 8388608;   // 73,728 B twiddle table (consumed by k_dftw)
    const unsigned short* TWt = (const unsigned short*)(ws + 6291456);  // 32 KB (in Ai, dead after k_dfth)
    const unsigned short* CWf = (const unsigned short*)(ws + 6301696);  // 6 KB
    // total workspace: 10,485,760 floats = 40 MiB

    k_twiddle<<<16, 256, 0, stream>>>(ws);
    k_dftw<<<1024, 256, 0, stream>>>(x, Ews, Ar, Ai);
    k_dfth<<<512, 256, 0, stream>>>(Ar, Ai, xfr, xfi);
    k_tables<<<64, 256, 0, stream>>>(conv_w, ws);     // after k_dfth: Ai region now dead
    k_mix<<<1024, 256, 0, stream>>>(xfr, xfi, w1r, w1i, w2r, w2i);
    k_idfth<<<512, 256, 0, stream>>>(xfr, xfi, T2);
    k_final<<<8192, 256, 0, stream>>>(x, CWf, TWt, conv_b, T2, out);
}